// Round 7
// baseline (159.403 us; speedup 1.0000x reference)
//
#include <hip/hip_runtime.h>

// CQT on gfx950 — v12 (resubmit; round-6 bench was an infra failure).
//   Wr[b,n] = sum_k kr[b,k]*wcos[k,n] - ki[b,k]*wsin[k,n]
//   Wi[b,n] = sum_k kr[b,k]*wsin[k,n] + ki[b,k]*wcos[k,n]
//   cqt[b,f] = sqrt((sum_n x[512f+n]*W[2b,n])^2 + (sum_n x[512f+n]*W[2b+1,n])^2)
// v10/v11 lessons: cqt occupancy must stay 12 waves/CU (v8 structure); NT hints
// and setprio reverted; A-reuse attacks a non-bottleneck (L1 dedups fg pairs).
// cqt is LDS-pipe-bound (3072 ds_read_b64/block ~10 us > MFMA 5 us).
// K1 wfused:  W = A' x Trig -> Wpf bf16 frag order. A'-frag computed in-kernel
//             from kr/ki (same bf16 rounding as old aprep — bit-identical);
//             trig in-register (phase exact int mod 2048, v_cos/v_sin revs).
//             384 tiles x 4 waves, K split 33/33/33/30, LDS reduce.
// K2 cqt:     grid 256 x 768, 12 waves = 2fg x 6mg, 64-frame blocks (= v8).
//             NEW: span-linear LDS with XOR swizzle byte^(((byte>>10)&7)<<4) ->
//             B-frag = ONE 16B-aligned conflict-free ds_read_b128 (was 2x b64
//             with 2-way-conflict pad layout). LDS pipe 24.6k -> 18.4k cyc/block.
//             A from Wpf frag-order, 8-deep double-buffered register prefetch.

#define HOPS 512
#define NBINS 84
#define FREQB 1025
#define NFRAMES 16381
#define TSAMP 8388608
#define SPAN 34304            // 63*512 + 2048  (shorts in span; 68,608 B LDS)

typedef short bf16x8 __attribute__((ext_vector_type(8)));
typedef float f32x16 __attribute__((ext_vector_type(16)));

union B8 { struct { ushort4 lo, hi; } p; bf16x8 v; uint4 u; };

__device__ __forceinline__ unsigned short f32_to_bf16(float f) {
    union { float f; unsigned u; } v; v.f = f;
    return (unsigned short)((v.u + 0x7FFFu + ((v.u >> 16) & 1u)) >> 16);
}
__device__ __forceinline__ unsigned pk_bf16(float lo, float hi) {
    return (unsigned)f32_to_bf16(lo) | ((unsigned)f32_to_bf16(hi) << 16);
}
__device__ __forceinline__ bf16x8 pack8(const float* s) {
    B8 r;
    r.u.x = pk_bf16(s[0], s[1]); r.u.y = pk_bf16(s[2], s[3]);
    r.u.z = pk_bf16(s[4], s[5]); r.u.w = pk_bf16(s[6], s[7]);
    return r.v;
}

// cos/sin with input in revolutions (maps to v_cos_f32 / v_sin_f32)
__device__ __forceinline__ float cos_rev(float r) { return __builtin_amdgcn_cosf(r); }
__device__ __forceinline__ float sin_rev(float r) { return __builtin_amdgcn_sinf(r); }

// ---------------- K1: fused W GEMM -> Wpf (frag order, bf16) ----------------
// grid 384 x 256: mt = bid>>6 (0..5), nt = bid&63. 4 waves split K (129 k16).
// Swapped mfma: D = Trig^T(32n x 16k) * A'^T(16k x 32row) = W^T tile.
//   A-operand lane (c32,h): Trig[n=nt*32+c32][k-run k16*16+h*8+j] (generated).
//   B-operand lane (c32,h): A'[mt*32+c32][same k-run] computed from kr/ki:
//     A'[2b][k]   = k<=1024 ? kr[b][k] : -ki[b][k-1025]
//     A'[2b+1][k] = k<=1024 ? ki[b][k] :  kr[b][k-1025]   (rows>=168 -> 0)
// D layout: lane col c32 = W-row-in-tile; D-row (=n_tile) = (r&3)+8*(r>>2)+4h.
// Frag store per quad g: Wpf[(mt*128 + nt*2 + (g>>1))*512 + (c32+32*(g&1))*8 + 4h + (r&3)]
__global__ __launch_bounds__(256) void wfused_kernel(
    const float* __restrict__ kr, const float* __restrict__ ki,
    unsigned short* __restrict__ Wpf)
{
    __shared__ float4 red[3][4][64];   // 12 KB cross-wave reduce

    const int bid = blockIdx.x;
    const int mt = bid >> 6, nt = bid & 63;
    const int t = threadIdx.x;
    const int w = t >> 6, l = t & 63;
    const int c32 = l & 31, h = l >> 5;
    const int n = nt * 32 + c32;

    const int row = mt * 32 + c32;
    const int b = row >> 1, im = row & 1;
    const bool bok = b < NBINS;
    const float* cosp = (im ? ki : kr) + (size_t)(bok ? b : 0) * FREQB;
    const float* sinp = (im ? kr : ki) + (size_t)(bok ? b : 0) * FREQB;
    const float ssign = im ? 1.f : -1.f;

    f32x16 acc;
    #pragma unroll
    for (int i = 0; i < 16; ++i) acc[i] = 0.f;

    const int k0 = w * 33;
    const int kcnt = (w < 3) ? 33 : 30;   // covers k16 = 0..128 (k up to 2049 nonzero)

    for (int i = 0; i < kcnt; ++i) {
        const int k16 = k0 + i;
        const int kb = k16 * 16 + h * 8;
        float tv[8], av[8];
        if (k16 <= 63) {                       // pure cos region
            #pragma unroll
            for (int j = 0; j < 8; ++j) {
                int p = __mul24(kb + j, n) & 2047;
                tv[j] = cos_rev((float)p * (1.f / 2048.f));
                av[j] = bok ? cosp[kb + j] : 0.f;
            }
        } else if (k16 >= 65 && k16 <= 127) {  // pure sin region (m = k-1025)
            const int mb = kb - 1025;
            #pragma unroll
            for (int j = 0; j < 8; ++j) {
                int p = __mul24(mb + j, n) & 2047;
                tv[j] = sin_rev((float)p * (1.f / 2048.f));
                av[j] = bok ? ssign * sinp[mb + j] : 0.f;
            }
        } else {                               // mixed k16==64 or 128 (+ zero tail)
            #pragma unroll
            for (int j = 0; j < 8; ++j) {
                int k = kb + j;
                float tvv = 0.f, avv = 0.f;
                if (k <= 1024) {
                    int p = __mul24(k, n) & 2047;
                    tvv = cos_rev((float)p * (1.f / 2048.f));
                    avv = bok ? cosp[k] : 0.f;
                } else if (k <= 2049) {
                    int p = __mul24(k - 1025, n) & 2047;
                    tvv = sin_rev((float)p * (1.f / 2048.f));
                    avv = bok ? ssign * sinp[k - 1025] : 0.f;
                }
                tv[j] = tvv; av[j] = avv;
            }
        }
        acc = __builtin_amdgcn_mfma_f32_32x32x16_bf16(pack8(tv), pack8(av), acc, 0, 0, 0);
    }

    if (w > 0) {
        #pragma unroll
        for (int q = 0; q < 4; ++q)
            red[w - 1][q][l] = make_float4(acc[4*q+0], acc[4*q+1], acc[4*q+2], acc[4*q+3]);
    }
    __syncthreads();
    if (w == 0) {
        #pragma unroll
        for (int s = 0; s < 3; ++s) {
            #pragma unroll
            for (int q = 0; q < 4; ++q) {
                float4 v = red[s][q][l];
                acc[4*q+0] += v.x; acc[4*q+1] += v.y;
                acc[4*q+2] += v.z; acc[4*q+3] += v.w;
            }
        }
        #pragma unroll
        for (int g = 0; g < 4; ++g) {
            uint2 qo;
            qo.x = pk_bf16(acc[4*g+0], acc[4*g+1]);
            qo.y = pk_bf16(acc[4*g+2], acc[4*g+3]);
            size_t off = (size_t)(mt * 128 + nt * 2 + (g >> 1)) * 512
                       + (size_t)(c32 + 32 * (g & 1)) * 8 + 4 * h;
            *(uint2*)(Wpf + off) = qo;   // 8B, coalesced 512B per g
        }
    }
}

// ---------------- K2: main GEMM, swizzled-b128 LDS, v8 structure ----------------
// grid 256 x 768. Block: frames f0..f0+63, all 192 rows. 12 waves: mg=w>>1 (32 rows),
// fg=w&1 (32 frames). mfma 32x32x16, acc 16. A from Wpf (frag order, coalesced),
// 8-step double-buffered register prefetch. B = one ds_read_b128 per k16 from
// XOR-swizzled span-linear LDS: byte_sw = byte ^ (((byte>>10)&7)<<4).
//   (16B cells: within a 128B stripe, lanes c32..c32+7 cover all 8 cells -> no
//    bank conflicts; XOR keeps 16B alignment and within-cell byte order.)
__global__ __launch_bounds__(768) void cqt_kernel(
    const float* __restrict__ x, const unsigned short* __restrict__ Wpf,
    float* __restrict__ out)
{
    __shared__ __align__(16) unsigned short xl[SPAN];   // 68,608 B

    const int t = threadIdx.x;
    const int f0 = blockIdx.x * 64;
    const long S0 = (long)f0 * HOPS;
    const int valid = (int)((TSAMP - S0) < (long)SPAN ? (TSAMP - S0) : (long)SPAN);

    // stage x-span once: 8576 float4 over 768 threads, swizzled 8B stores
    #pragma unroll
    for (int i = 0; i < 12; ++i) {
        int idx4 = t + i * 768;
        if (idx4 < 8576) {
            int s = idx4 * 4;
            float4 v = make_float4(0.f, 0.f, 0.f, 0.f);
            if (s + 4 <= valid) v = *(const float4*)(x + S0 + s);
            ushort4 o;
            o.x = f32_to_bf16(v.x); o.y = f32_to_bf16(v.y);
            o.z = f32_to_bf16(v.z); o.w = f32_to_bf16(v.w);
            int byte = idx4 * 8;
            int bsw = byte ^ (((byte >> 10) & 7) << 4);
            *(ushort4*)((char*)xl + bsw) = o;
        }
    }
    __syncthreads();   // the only barrier

    const int w = t >> 6, l = t & 63;
    const int mg = w >> 1, fg = w & 1;
    const int c32 = l & 31, h = l >> 5;

    const unsigned short* apf = Wpf + (size_t)mg * (128 * 512) + (size_t)l * 8;  // +k16*512
    const int byteBase = (fg * 32 + c32) * 1024 + h * 16;

    f32x16 acc;
    #pragma unroll
    for (int i = 0; i < 16; ++i) acc[i] = 0.f;

    auto ldsB = [&](int k16) -> bf16x8 {
        int byte = byteBase + k16 * 32;
        int bsw = byte ^ (((byte >> 10) & 7) << 4);
        B8 r;
        r.u = *(const uint4*)((const char*)xl + bsw);
        return r.v;
    };

    uint4 Abuf[2][8];
    #pragma unroll
    for (int j = 0; j < 8; ++j)
        Abuf[0][j] = *(const uint4*)(apf + (size_t)j * 512);

    #pragma unroll
    for (int c = 0; c < 16; ++c) {
        const int cur = c & 1, nxt = cur ^ 1;
        if (c < 15) {
            #pragma unroll
            for (int j = 0; j < 8; ++j)
                Abuf[nxt][j] = *(const uint4*)(apf + (size_t)((c + 1) * 8 + j) * 512);
        }
        #pragma unroll
        for (int j = 0; j < 8; ++j) {
            B8 af; af.u = Abuf[cur][j];
            acc = __builtin_amdgcn_mfma_f32_32x32x16_bf16(af.v, ldsB(c * 8 + j), acc, 0, 0, 0);
        }
    }

    // epilogue: C/D col=c32 (f), row=(r&3)+8*(r>>2)+4*h; (Wr,Wi) pairs -> magnitude
    const int f = f0 + fg * 32 + c32;
    if (f < NFRAMES) {
        #pragma unroll
        for (int rp = 0; rp < 4; ++rp) {
            int base = mg * 32 + 8 * rp + 4 * h;   // even
            int b0 = base >> 1;
            float r0 = acc[4 * rp + 0], i0 = acc[4 * rp + 1];
            float r1 = acc[4 * rp + 2], i1 = acc[4 * rp + 3];
            if (b0 < NBINS)
                out[(size_t)b0 * NFRAMES + f] = sqrtf(r0 * r0 + i0 * i0);
            if (b0 + 1 < NBINS)
                out[(size_t)(b0 + 1) * NFRAMES + f] = sqrtf(r1 * r1 + i1 * i1);
        }
    }
}

extern "C" void kernel_launch(void* const* d_in, const int* in_sizes, int n_in,
                              void* d_out, int out_size, void* d_ws, size_t ws_size,
                              hipStream_t stream) {
    const float* x    = (const float*)d_in[0];
    // d_in[1] (wcos) and d_in[2] (wsin) unused — trig generated on-device.
    const float* kr   = (const float*)d_in[3];
    const float* ki   = (const float*)d_in[4];
    float* out = (float*)d_out;

    unsigned short* Wpf = (unsigned short*)d_ws;   // 786,432 B

    wfused_kernel<<<dim3(384), dim3(256), 0, stream>>>(kr, ki, Wpf);
    cqt_kernel<<<dim3(256), dim3(768), 0, stream>>>(x, Wpf, out);
}

// Round 8
// 120.858 us; speedup vs baseline: 1.3189x; 1.3189x over previous
//
#include <hip/hip_runtime.h>

// CQT on gfx950 — v13: v8 pipeline (aprep + Apf-reading wfused) + v12 swizzled cqt.
//   Wr[b,n] = sum_k kr[b,k]*wcos[k,n] - ki[b,k]*wsin[k,n]
//   Wi[b,n] = sum_k kr[b,k]*wsin[k,n] + ki[b,k]*wcos[k,n]
//   cqt[b,f] = sqrt((sum_n x[512f+n]*W[2b,n])^2 + (sum_n x[512f+n]*W[2b+1,n])^2)
// v12 lesson (measured): fusing aprep's uncoalesced kr/ki reads into wfused made
// every VMEM inst touch 64 lines x 264 insts/wave at 6 waves/CU -> 61 us
// latency-bound (MfmaUtil 0.9%, FETCH 2.7MB). aprep does them ONCE at 828-block
// parallelism (~2 us). Meanwhile v12's swizzled cqt gained ~12 us. Recombine.
// K1 aprep:   Apf = A'[192][2208] bf16 in MFMA-frag order [mt][k16][lane]x8.
// K2 wfused:  W = A' x Trig -> Wpf bf16 frag order; A-frags = coalesced uint4
//             from Apf; trig in-register (phase exact int mod 2048, v_cos/v_sin
//             revolutions). 384 tiles x 4 waves, K split 33/33/33/30, LDS reduce.
// K3 cqt:     grid 256 x 768, 12 waves = 2fg x 6mg, 64-frame blocks.
//             Span-linear LDS, XOR swizzle byte^(((byte>>10)&7)<<4) -> B-frag is
//             ONE conflict-free 16B ds_read_b128. A from Wpf frag-order with
//             8-deep double-buffered register prefetch.

#define HOPS 512
#define NBINS 84
#define FREQB 1025
#define NFRAMES 16381
#define TSAMP 8388608
#define SPAN 34304            // 63*512 + 2048  (shorts in span; 68,608 B LDS)
#define KP16 138              // k16 slots in A' K dim (2208)

typedef short bf16x8 __attribute__((ext_vector_type(8)));
typedef float f32x16 __attribute__((ext_vector_type(16)));

union B8 { struct { ushort4 lo, hi; } p; bf16x8 v; uint4 u; };

__device__ __forceinline__ unsigned short f32_to_bf16(float f) {
    union { float f; unsigned u; } v; v.f = f;
    return (unsigned short)((v.u + 0x7FFFu + ((v.u >> 16) & 1u)) >> 16);
}
__device__ __forceinline__ unsigned pk_bf16(float lo, float hi) {
    return (unsigned)f32_to_bf16(lo) | ((unsigned)f32_to_bf16(hi) << 16);
}
__device__ __forceinline__ bf16x8 pack8(const float* s) {
    B8 r;
    r.u.x = pk_bf16(s[0], s[1]); r.u.y = pk_bf16(s[2], s[3]);
    r.u.z = pk_bf16(s[4], s[5]); r.u.w = pk_bf16(s[6], s[7]);
    return r.v;
}

// cos/sin with input in revolutions (maps to v_cos_f32 / v_sin_f32)
__device__ __forceinline__ float cos_rev(float r) { return __builtin_amdgcn_cosf(r); }
__device__ __forceinline__ float sin_rev(float r) { return __builtin_amdgcn_sinf(r); }

// ---------------- K1: A' prep into frag order ----------------
// grid 828 x 64: bid = mt*138 + k16. lane l: c32=l&31, h=l>>5.
// Apf[(mt*138+k16)*512 + l*8 + j] = A'[mt*32+c32][k16*16+h*8+j]
__global__ __launch_bounds__(64) void aprep_kernel(
    const float* __restrict__ kr, const float* __restrict__ ki,
    unsigned short* __restrict__ Apf)
{
    const int bid = blockIdx.x;
    const int mt = bid / KP16, k16 = bid % KP16;
    const int l = threadIdx.x;
    const int c32 = l & 31, h = l >> 5;
    const int row = mt * 32 + c32;
    const int b = row >> 1, im = row & 1;
    const bool bok = b < NBINS;
    const float* cosp = (im ? ki : kr) + (size_t)(bok ? b : 0) * FREQB;
    const float* sinp = (im ? kr : ki) + (size_t)(bok ? b : 0) * FREQB;
    const float ssign = im ? 1.f : -1.f;

    unsigned short o[8];
    #pragma unroll
    for (int j = 0; j < 8; ++j) {
        int k = k16 * 16 + h * 8 + j;
        float v = 0.f;
        if (bok) {
            if (k <= 1024)       v = cosp[k];
            else if (k <= 2049)  v = ssign * sinp[k - 1025];
        }
        o[j] = f32_to_bf16(v);
    }
    uint4 pk;
    pk.x = (unsigned)o[0] | ((unsigned)o[1] << 16);
    pk.y = (unsigned)o[2] | ((unsigned)o[3] << 16);
    pk.z = (unsigned)o[4] | ((unsigned)o[5] << 16);
    pk.w = (unsigned)o[6] | ((unsigned)o[7] << 16);
    *(uint4*)(Apf + (size_t)bid * 512 + (size_t)l * 8) = pk;
}

// ---------------- K2: fused W GEMM -> Wpf (frag order, bf16) ----------------
// grid 384 x 256: mt = bid>>6 (0..5), nt = bid&63. 4 waves split K (129 k16).
// Swapped mfma: D = Trig^T(32n x 16k) * A'^T(16k x 32row) = W^T tile.
//   A-operand lane (c32,h): Trig[n=nt*32+c32][k-run k16*16+h*8+j] (generated).
//   B-operand lane (c32,h): A'[mt*32+c32][same k-run] = coalesced uint4 from Apf.
// D layout: lane col c32 = W-row-in-tile; D-row (=n_tile) = (r&3)+8*(r>>2)+4h.
// Frag store per quad g: Wpf[(mt*128 + nt*2 + (g>>1))*512 + (c32+32*(g&1))*8 + 4h + (r&3)]
__global__ __launch_bounds__(256) void wfused_kernel(
    const unsigned short* __restrict__ Apf, unsigned short* __restrict__ Wpf)
{
    __shared__ float4 red[3][4][64];   // 12 KB cross-wave reduce

    const int bid = blockIdx.x;
    const int mt = bid >> 6, nt = bid & 63;
    const int t = threadIdx.x;
    const int w = t >> 6, l = t & 63;
    const int c32 = l & 31, h = l >> 5;
    const int n = nt * 32 + c32;

    f32x16 acc;
    #pragma unroll
    for (int i = 0; i < 16; ++i) acc[i] = 0.f;

    const int k0 = w * 33;
    const int kcnt = (w < 3) ? 33 : 30;   // covers k16 = 0..128 (k up to 2049 nonzero)
    const unsigned short* ap = Apf + (size_t)(mt * KP16 + k0) * 512 + (size_t)l * 8;

    for (int i = 0; i < kcnt; ++i) {
        const int k16 = k0 + i;
        B8 bf; bf.u = *(const uint4*)(ap + (size_t)i * 512);
        float tv[8];
        const int kb = k16 * 16 + h * 8;
        if (k16 <= 63) {                       // pure cos rows
            #pragma unroll
            for (int j = 0; j < 8; ++j) {
                int p = __mul24(kb + j, n) & 2047;
                tv[j] = cos_rev((float)p * (1.f / 2048.f));
            }
        } else if (k16 >= 65 && k16 <= 127) {  // pure sin rows (m = k-1025)
            #pragma unroll
            for (int j = 0; j < 8; ++j) {
                int p = __mul24(kb + j - 1025, n) & 2047;
                tv[j] = sin_rev((float)p * (1.f / 2048.f));
            }
        } else {                               // mixed k16==64 or 128 (+ zero tail)
            #pragma unroll
            for (int j = 0; j < 8; ++j) {
                int k = kb + j;
                float v = 0.f;
                if (k <= 1024) {
                    int p = __mul24(k, n) & 2047;
                    v = cos_rev((float)p * (1.f / 2048.f));
                } else if (k <= 2049) {
                    int p = __mul24(k - 1025, n) & 2047;
                    v = sin_rev((float)p * (1.f / 2048.f));
                }
                tv[j] = v;
            }
        }
        acc = __builtin_amdgcn_mfma_f32_32x32x16_bf16(pack8(tv), bf.v, acc, 0, 0, 0);
    }

    if (w > 0) {
        #pragma unroll
        for (int q = 0; q < 4; ++q)
            red[w - 1][q][l] = make_float4(acc[4*q+0], acc[4*q+1], acc[4*q+2], acc[4*q+3]);
    }
    __syncthreads();
    if (w == 0) {
        #pragma unroll
        for (int s = 0; s < 3; ++s) {
            #pragma unroll
            for (int q = 0; q < 4; ++q) {
                float4 v = red[s][q][l];
                acc[4*q+0] += v.x; acc[4*q+1] += v.y;
                acc[4*q+2] += v.z; acc[4*q+3] += v.w;
            }
        }
        #pragma unroll
        for (int g = 0; g < 4; ++g) {
            uint2 qo;
            qo.x = pk_bf16(acc[4*g+0], acc[4*g+1]);
            qo.y = pk_bf16(acc[4*g+2], acc[4*g+3]);
            size_t off = (size_t)(mt * 128 + nt * 2 + (g >> 1)) * 512
                       + (size_t)(c32 + 32 * (g & 1)) * 8 + 4 * h;
            *(uint2*)(Wpf + off) = qo;   // 8B, coalesced 512B per g
        }
    }
}

// ---------------- K3: main GEMM, swizzled-b128 LDS, v8 structure ----------------
// grid 256 x 768. Block: frames f0..f0+63, all 192 rows. 12 waves: mg=w>>1 (32 rows),
// fg=w&1 (32 frames). mfma 32x32x16, acc 16. A from Wpf (frag order, coalesced),
// 8-step double-buffered register prefetch. B = one ds_read_b128 per k16 from
// XOR-swizzled span-linear LDS: byte_sw = byte ^ (((byte>>10)&7)<<4).
//   (16B cells: within a 128B stripe, lanes c32..c32+7 cover all 8 cells -> no
//    bank conflicts; XOR keeps 16B alignment and within-cell byte order.)
__global__ __launch_bounds__(768) void cqt_kernel(
    const float* __restrict__ x, const unsigned short* __restrict__ Wpf,
    float* __restrict__ out)
{
    __shared__ __align__(16) unsigned short xl[SPAN];   // 68,608 B

    const int t = threadIdx.x;
    const int f0 = blockIdx.x * 64;
    const long S0 = (long)f0 * HOPS;
    const int valid = (int)((TSAMP - S0) < (long)SPAN ? (TSAMP - S0) : (long)SPAN);

    // stage x-span once: 8576 float4 over 768 threads, swizzled 8B stores
    #pragma unroll
    for (int i = 0; i < 12; ++i) {
        int idx4 = t + i * 768;
        if (idx4 < 8576) {
            int s = idx4 * 4;
            float4 v = make_float4(0.f, 0.f, 0.f, 0.f);
            if (s + 4 <= valid) v = *(const float4*)(x + S0 + s);
            ushort4 o;
            o.x = f32_to_bf16(v.x); o.y = f32_to_bf16(v.y);
            o.z = f32_to_bf16(v.z); o.w = f32_to_bf16(v.w);
            int byte = idx4 * 8;
            int bsw = byte ^ (((byte >> 10) & 7) << 4);
            *(ushort4*)((char*)xl + bsw) = o;
        }
    }
    __syncthreads();   // the only barrier

    const int w = t >> 6, l = t & 63;
    const int mg = w >> 1, fg = w & 1;
    const int c32 = l & 31, h = l >> 5;

    const unsigned short* apf = Wpf + (size_t)mg * (128 * 512) + (size_t)l * 8;  // +k16*512
    const int byteBase = (fg * 32 + c32) * 1024 + h * 16;

    f32x16 acc;
    #pragma unroll
    for (int i = 0; i < 16; ++i) acc[i] = 0.f;

    auto ldsB = [&](int k16) -> bf16x8 {
        int byte = byteBase + k16 * 32;
        int bsw = byte ^ (((byte >> 10) & 7) << 4);
        B8 r;
        r.u = *(const uint4*)((const char*)xl + bsw);
        return r.v;
    };

    uint4 Abuf[2][8];
    #pragma unroll
    for (int j = 0; j < 8; ++j)
        Abuf[0][j] = *(const uint4*)(apf + (size_t)j * 512);

    #pragma unroll
    for (int c = 0; c < 16; ++c) {
        const int cur = c & 1, nxt = cur ^ 1;
        if (c < 15) {
            #pragma unroll
            for (int j = 0; j < 8; ++j)
                Abuf[nxt][j] = *(const uint4*)(apf + (size_t)((c + 1) * 8 + j) * 512);
        }
        #pragma unroll
        for (int j = 0; j < 8; ++j) {
            B8 af; af.u = Abuf[cur][j];
            acc = __builtin_amdgcn_mfma_f32_32x32x16_bf16(af.v, ldsB(c * 8 + j), acc, 0, 0, 0);
        }
    }

    // epilogue: C/D col=c32 (f), row=(r&3)+8*(r>>2)+4*h; (Wr,Wi) pairs -> magnitude
    const int f = f0 + fg * 32 + c32;
    if (f < NFRAMES) {
        #pragma unroll
        for (int rp = 0; rp < 4; ++rp) {
            int base = mg * 32 + 8 * rp + 4 * h;   // even
            int b0 = base >> 1;
            float r0 = acc[4 * rp + 0], i0 = acc[4 * rp + 1];
            float r1 = acc[4 * rp + 2], i1 = acc[4 * rp + 3];
            if (b0 < NBINS)
                out[(size_t)b0 * NFRAMES + f] = sqrtf(r0 * r0 + i0 * i0);
            if (b0 + 1 < NBINS)
                out[(size_t)(b0 + 1) * NFRAMES + f] = sqrtf(r1 * r1 + i1 * i1);
        }
    }
}

extern "C" void kernel_launch(void* const* d_in, const int* in_sizes, int n_in,
                              void* d_out, int out_size, void* d_ws, size_t ws_size,
                              hipStream_t stream) {
    const float* x    = (const float*)d_in[0];
    // d_in[1] (wcos) and d_in[2] (wsin) unused — trig generated on-device.
    const float* kr   = (const float*)d_in[3];
    const float* ki   = (const float*)d_in[4];
    float* out = (float*)d_out;

    unsigned short* Wpf = (unsigned short*)d_ws;                    // 786,432 B
    unsigned short* Apf = (unsigned short*)((char*)d_ws + 786432);  // 847,872 B

    aprep_kernel<<<dim3(6 * KP16), dim3(64), 0, stream>>>(kr, ki, Apf);
    wfused_kernel<<<dim3(384), dim3(256), 0, stream>>>(Apf, Wpf);
    cqt_kernel<<<dim3(256), dim3(768), 0, stream>>>(x, Wpf, out);
}

// Round 9
// 117.716 us; speedup vs baseline: 1.3541x; 1.0267x over previous
//
#include <hip/hip_runtime.h>

// CQT on gfx950 — v14: coalesced aprep + 8-wave wfused (attack the 23us precompute).
//   Wr[b,n] = sum_k kr[b,k]*wcos[k,n] - ki[b,k]*wsin[k,n]
//   Wi[b,n] = sum_k kr[b,k]*wsin[k,n] + ki[b,k]*wcos[k,n]
//   cqt[b,f] = sqrt((sum_n x[512f+n]*W[2b,n])^2 + (sum_n x[512f+n]*W[2b+1,n])^2)
// v12/v13 algebra: fixed+cqt = 97.9, aprep+wfused = 23us (!). aprep gathers 64
// rows/inst on flush-cold cache (latency-serialized); wfused runs 1.5 waves/SIMD
// on issue-bound trig. Fix both without changing any numerics of the outputs.
// K1 aprep:   TRANSPOSED addressing: block = one A'-row x 512-k chunk; lane reads
//             8 consecutive floats (coalesced, L1-reused); scattered posted 16B
//             store into frag order. Output bit-identical to v13's aprep.
// K2 wfused:  W = A' x Trig -> Wpf bf16 frag order; A-frags coalesced from Apf;
//             trig in-register (phase exact int mod 2048, v_cos/v_sin revs).
//             v14: 8 waves/block (512 thr), K split 17+7x16, 7-entry LDS reduce.
// K3 cqt:     (= v13) grid 256 x 768, 12 waves = 2fg x 6mg, 64-frame blocks.
//             Span-linear LDS, XOR swizzle byte^(((byte>>10)&7)<<4), B-frag is
//             one conflict-free ds_read_b128; A 8-deep double-buffered prefetch.

#define HOPS 512
#define NBINS 84
#define FREQB 1025
#define NFRAMES 16381
#define TSAMP 8388608
#define SPAN 34304            // 63*512 + 2048  (shorts in span; 68,608 B LDS)
#define KP16 138              // k16 slots in A' K dim (2208)

typedef short bf16x8 __attribute__((ext_vector_type(8)));
typedef float f32x16 __attribute__((ext_vector_type(16)));

union B8 { struct { ushort4 lo, hi; } p; bf16x8 v; uint4 u; };

__device__ __forceinline__ unsigned short f32_to_bf16(float f) {
    union { float f; unsigned u; } v; v.f = f;
    return (unsigned short)((v.u + 0x7FFFu + ((v.u >> 16) & 1u)) >> 16);
}
__device__ __forceinline__ unsigned pk_bf16(float lo, float hi) {
    return (unsigned)f32_to_bf16(lo) | ((unsigned)f32_to_bf16(hi) << 16);
}
__device__ __forceinline__ bf16x8 pack8(const float* s) {
    B8 r;
    r.u.x = pk_bf16(s[0], s[1]); r.u.y = pk_bf16(s[2], s[3]);
    r.u.z = pk_bf16(s[4], s[5]); r.u.w = pk_bf16(s[6], s[7]);
    return r.v;
}

// cos/sin with input in revolutions (maps to v_cos_f32 / v_sin_f32)
__device__ __forceinline__ float cos_rev(float r) { return __builtin_amdgcn_cosf(r); }
__device__ __forceinline__ float sin_rev(float r) { return __builtin_amdgcn_sinf(r); }

// ---------------- K1: A' prep, coalesced reads, scattered frag-order stores ----
// grid 960 x 64: bid = row*5 + c. Lane l: q = c*64 + l (uint4 index, q<276),
// k-run = q*8 .. q*8+7 (CONSECUTIVE -> coalesced reads, stride-32B lanes).
// Dest (frag order): mt=row>>5, c32=row&31, k16=q>>1, h=q&1:
//   Apf[(mt*138+k16)*512 + (h*32+c32)*8 .. +8]  (16B posted store, scattered ok)
__global__ __launch_bounds__(64) void aprep_kernel(
    const float* __restrict__ kr, const float* __restrict__ ki,
    unsigned short* __restrict__ Apf)
{
    const int bid = blockIdx.x;
    const int row = bid / 5, c = bid % 5;
    const int l = threadIdx.x;
    const int q = c * 64 + l;
    if (q >= 276) return;

    const int b = row >> 1, im = row & 1;
    const bool bok = b < NBINS;
    const float* cosp = (im ? ki : kr) + (size_t)(bok ? b : 0) * FREQB;
    const float* sinp = (im ? kr : ki) + (size_t)(bok ? b : 0) * FREQB;
    const float ssign = im ? 1.f : -1.f;

    const int k0 = q * 8;
    unsigned short o[8];
    #pragma unroll
    for (int j = 0; j < 8; ++j) {
        int k = k0 + j;
        float v = 0.f;
        if (bok) {
            if (k <= 1024)       v = cosp[k];
            else if (k <= 2049)  v = ssign * sinp[k - 1025];
        }
        o[j] = f32_to_bf16(v);
    }
    uint4 pk;
    pk.x = (unsigned)o[0] | ((unsigned)o[1] << 16);
    pk.y = (unsigned)o[2] | ((unsigned)o[3] << 16);
    pk.z = (unsigned)o[4] | ((unsigned)o[5] << 16);
    pk.w = (unsigned)o[6] | ((unsigned)o[7] << 16);

    const int mt = row >> 5, c32 = row & 31;
    const int k16 = q >> 1, h = q & 1;
    *(uint4*)(Apf + (size_t)(mt * KP16 + k16) * 512 + (size_t)(h * 32 + c32) * 8) = pk;
}

// ---------------- K2: fused W GEMM -> Wpf (frag order, bf16) ----------------
// grid 384 x 512: mt = bid>>6 (0..5), nt = bid&63. 8 waves split K (129 k16:
// w0 17, w1-7 16). Swapped mfma: D = Trig^T(32n x 16k) * A'^T(16k x 32row).
//   A-operand lane (c32,h): Trig[n=nt*32+c32][k-run k16*16+h*8+j] (generated).
//   B-operand lane (c32,h): A'[mt*32+c32][same k-run] = coalesced uint4 from Apf.
// D layout: lane col c32 = W-row-in-tile; D-row (=n_tile) = (r&3)+8*(r>>2)+4h.
// Frag store per quad g: Wpf[(mt*128 + nt*2 + (g>>1))*512 + (c32+32*(g&1))*8 + 4h + (r&3)]
__global__ __launch_bounds__(512) void wfused_kernel(
    const unsigned short* __restrict__ Apf, unsigned short* __restrict__ Wpf)
{
    __shared__ float4 red[7][4][64];   // 28 KB cross-wave reduce

    const int bid = blockIdx.x;
    const int mt = bid >> 6, nt = bid & 63;
    const int t = threadIdx.x;
    const int w = t >> 6, l = t & 63;
    const int c32 = l & 31, h = l >> 5;
    const int n = nt * 32 + c32;

    f32x16 acc;
    #pragma unroll
    for (int i = 0; i < 16; ++i) acc[i] = 0.f;

    const int k0 = (w == 0) ? 0 : 16 * w + 1;
    const int kcnt = (w == 0) ? 17 : 16;   // covers k16 = 0..128
    const unsigned short* ap = Apf + (size_t)(mt * KP16 + k0) * 512 + (size_t)l * 8;

    for (int i = 0; i < kcnt; ++i) {
        const int k16 = k0 + i;
        B8 bf; bf.u = *(const uint4*)(ap + (size_t)i * 512);
        float tv[8];
        const int kb = k16 * 16 + h * 8;
        if (k16 <= 63) {                       // pure cos rows
            #pragma unroll
            for (int j = 0; j < 8; ++j) {
                int p = __mul24(kb + j, n) & 2047;
                tv[j] = cos_rev((float)p * (1.f / 2048.f));
            }
        } else if (k16 >= 65 && k16 <= 127) {  // pure sin rows (m = k-1025)
            #pragma unroll
            for (int j = 0; j < 8; ++j) {
                int p = __mul24(kb + j - 1025, n) & 2047;
                tv[j] = sin_rev((float)p * (1.f / 2048.f));
            }
        } else {                               // mixed k16==64 or 128 (+ zero tail)
            #pragma unroll
            for (int j = 0; j < 8; ++j) {
                int k = kb + j;
                float v = 0.f;
                if (k <= 1024) {
                    int p = __mul24(k, n) & 2047;
                    v = cos_rev((float)p * (1.f / 2048.f));
                } else if (k <= 2049) {
                    int p = __mul24(k - 1025, n) & 2047;
                    v = sin_rev((float)p * (1.f / 2048.f));
                }
                tv[j] = v;
            }
        }
        acc = __builtin_amdgcn_mfma_f32_32x32x16_bf16(pack8(tv), bf.v, acc, 0, 0, 0);
    }

    if (w > 0) {
        #pragma unroll
        for (int q = 0; q < 4; ++q)
            red[w - 1][q][l] = make_float4(acc[4*q+0], acc[4*q+1], acc[4*q+2], acc[4*q+3]);
    }
    __syncthreads();
    if (w == 0) {
        #pragma unroll
        for (int s = 0; s < 7; ++s) {
            #pragma unroll
            for (int q = 0; q < 4; ++q) {
                float4 v = red[s][q][l];
                acc[4*q+0] += v.x; acc[4*q+1] += v.y;
                acc[4*q+2] += v.z; acc[4*q+3] += v.w;
            }
        }
        #pragma unroll
        for (int g = 0; g < 4; ++g) {
            uint2 qo;
            qo.x = pk_bf16(acc[4*g+0], acc[4*g+1]);
            qo.y = pk_bf16(acc[4*g+2], acc[4*g+3]);
            size_t off = (size_t)(mt * 128 + nt * 2 + (g >> 1)) * 512
                       + (size_t)(c32 + 32 * (g & 1)) * 8 + 4 * h;
            *(uint2*)(Wpf + off) = qo;   // 8B, coalesced 512B per g
        }
    }
}

// ---------------- K3: main GEMM, swizzled-b128 LDS, v8 structure ----------------
// grid 256 x 768. Block: frames f0..f0+63, all 192 rows. 12 waves: mg=w>>1 (32 rows),
// fg=w&1 (32 frames). mfma 32x32x16, acc 16. A from Wpf (frag order, coalesced),
// 8-step double-buffered register prefetch. B = one ds_read_b128 per k16 from
// XOR-swizzled span-linear LDS: byte_sw = byte ^ (((byte>>10)&7)<<4).
__global__ __launch_bounds__(768) void cqt_kernel(
    const float* __restrict__ x, const unsigned short* __restrict__ Wpf,
    float* __restrict__ out)
{
    __shared__ __align__(16) unsigned short xl[SPAN];   // 68,608 B

    const int t = threadIdx.x;
    const int f0 = blockIdx.x * 64;
    const long S0 = (long)f0 * HOPS;
    const int valid = (int)((TSAMP - S0) < (long)SPAN ? (TSAMP - S0) : (long)SPAN);

    // stage x-span once: 8576 float4 over 768 threads, swizzled 8B stores
    #pragma unroll
    for (int i = 0; i < 12; ++i) {
        int idx4 = t + i * 768;
        if (idx4 < 8576) {
            int s = idx4 * 4;
            float4 v = make_float4(0.f, 0.f, 0.f, 0.f);
            if (s + 4 <= valid) v = *(const float4*)(x + S0 + s);
            ushort4 o;
            o.x = f32_to_bf16(v.x); o.y = f32_to_bf16(v.y);
            o.z = f32_to_bf16(v.z); o.w = f32_to_bf16(v.w);
            int byte = idx4 * 8;
            int bsw = byte ^ (((byte >> 10) & 7) << 4);
            *(ushort4*)((char*)xl + bsw) = o;
        }
    }
    __syncthreads();   // the only barrier

    const int w = t >> 6, l = t & 63;
    const int mg = w >> 1, fg = w & 1;
    const int c32 = l & 31, h = l >> 5;

    const unsigned short* apf = Wpf + (size_t)mg * (128 * 512) + (size_t)l * 8;  // +k16*512
    const int byteBase = (fg * 32 + c32) * 1024 + h * 16;

    f32x16 acc;
    #pragma unroll
    for (int i = 0; i < 16; ++i) acc[i] = 0.f;

    auto ldsB = [&](int k16) -> bf16x8 {
        int byte = byteBase + k16 * 32;
        int bsw = byte ^ (((byte >> 10) & 7) << 4);
        B8 r;
        r.u = *(const uint4*)((const char*)xl + bsw);
        return r.v;
    };

    uint4 Abuf[2][8];
    #pragma unroll
    for (int j = 0; j < 8; ++j)
        Abuf[0][j] = *(const uint4*)(apf + (size_t)j * 512);

    #pragma unroll
    for (int c = 0; c < 16; ++c) {
        const int cur = c & 1, nxt = cur ^ 1;
        if (c < 15) {
            #pragma unroll
            for (int j = 0; j < 8; ++j)
                Abuf[nxt][j] = *(const uint4*)(apf + (size_t)((c + 1) * 8 + j) * 512);
        }
        #pragma unroll
        for (int j = 0; j < 8; ++j) {
            B8 af; af.u = Abuf[cur][j];
            acc = __builtin_amdgcn_mfma_f32_32x32x16_bf16(af.v, ldsB(c * 8 + j), acc, 0, 0, 0);
        }
    }

    // epilogue: C/D col=c32 (f), row=(r&3)+8*(r>>2)+4*h; (Wr,Wi) pairs -> magnitude
    const int f = f0 + fg * 32 + c32;
    if (f < NFRAMES) {
        #pragma unroll
        for (int rp = 0; rp < 4; ++rp) {
            int base = mg * 32 + 8 * rp + 4 * h;   // even
            int b0 = base >> 1;
            float r0 = acc[4 * rp + 0], i0 = acc[4 * rp + 1];
            float r1 = acc[4 * rp + 2], i1 = acc[4 * rp + 3];
            if (b0 < NBINS)
                out[(size_t)b0 * NFRAMES + f] = sqrtf(r0 * r0 + i0 * i0);
            if (b0 + 1 < NBINS)
                out[(size_t)(b0 + 1) * NFRAMES + f] = sqrtf(r1 * r1 + i1 * i1);
        }
    }
}

extern "C" void kernel_launch(void* const* d_in, const int* in_sizes, int n_in,
                              void* d_out, int out_size, void* d_ws, size_t ws_size,
                              hipStream_t stream) {
    const float* x    = (const float*)d_in[0];
    // d_in[1] (wcos) and d_in[2] (wsin) unused — trig generated on-device.
    const float* kr   = (const float*)d_in[3];
    const float* ki   = (const float*)d_in[4];
    float* out = (float*)d_out;

    unsigned short* Wpf = (unsigned short*)d_ws;                    // 786,432 B
    unsigned short* Apf = (unsigned short*)((char*)d_ws + 786432);  // 847,872 B

    aprep_kernel<<<dim3(960), dim3(64), 0, stream>>>(kr, ki, Apf);
    wfused_kernel<<<dim3(384), dim3(512), 0, stream>>>(Apf, Wpf);
    cqt_kernel<<<dim3(256), dim3(768), 0, stream>>>(x, Wpf, out);
}